// Round 1
// baseline (736.007 us; speedup 1.0000x reference)
//
#include <hip/hip_runtime.h>

#define N_NODES 16384
#define N_EDGES 262144
#define HID 512
#define NG 256
#define NL 4
#define NOUT 128

typedef __attribute__((ext_vector_type(8))) short bf16x8;
typedef __attribute__((ext_vector_type(4))) float f32x4;

static __device__ __forceinline__ unsigned short f2bf(float f) {
    unsigned int u = __float_as_uint(f);
    unsigned int r = (u + 0x7fffu + ((u >> 16) & 1u)) >> 16;
    return (unsigned short)r;
}

// ---------------- CSR build (dst-grouped edge lists) ----------------
__global__ void k_count(const int* __restrict__ dst, int* __restrict__ cnt) {
    int e = blockIdx.x * 256 + threadIdx.x;
    atomicAdd(&cnt[dst[e]], 1);
}

__global__ void k_scan(const int* __restrict__ cnt, int* __restrict__ rs) {
    __shared__ int spre[256];
    int t = threadIdx.x;
    int base = t * 64;
    int s = 0;
    for (int i = 0; i < 64; ++i) s += cnt[base + i];
    spre[t] = s;
    __syncthreads();
    if (t == 0) {
        int run = 0;
        for (int i = 0; i < 256; ++i) { int v = spre[i]; spre[i] = run; run += v; }
        rs[N_NODES] = run;
    }
    __syncthreads();
    int run = spre[t];
    for (int i = 0; i < 64; ++i) { rs[base + i] = run; run += cnt[base + i]; }
}

__global__ void k_fill(const int* __restrict__ dst, const int* __restrict__ rs,
                       int* __restrict__ fc, int* __restrict__ eid) {
    int e = blockIdx.x * 256 + threadIdx.x;
    int d = dst[e];
    int pos = atomicAdd(&fc[d], 1);
    eid[rs[d] + pos] = e;
}

__global__ void k_gstart(const int* __restrict__ gid, int* __restrict__ gs) {
    int g = threadIdx.x;  // 256 threads, gid is sorted
    int lo = 0, hi = N_NODES;
    while (lo < hi) { int mid = (lo + hi) >> 1; if (gid[mid] < g) lo = mid + 1; else hi = mid; }
    gs[g] = lo;
    if (g == 0) gs[NG] = N_NODES;
}

// ---------------- Atom encoder: h[n,:] = sum_f atom_emb[f, idx, :] ----------------
__global__ void k_atom(const int* __restrict__ hn, const float* __restrict__ emb,
                       float* __restrict__ h) {
    int n = blockIdx.x;
    int c = threadIdx.x * 4;  // 128 threads * float4 = 512
    float4 acc = make_float4(0.f, 0.f, 0.f, 0.f);
    for (int f = 0; f < 9; ++f) {
        int v = hn[n * 9 + f];
        const float4 ev = *(const float4*)(emb + (size_t)(f * 128 + v) * HID + c);
        acc.x += ev.x; acc.y += ev.y; acc.z += ev.z; acc.w += ev.w;
    }
    *(float4*)(h + (size_t)n * HID + c) = acc;
}

// ---------------- W transpose + bf16 convert: Wt[l][n][k] = W[l][k][n] ----------------
__global__ void k_wt(const float* __restrict__ W, unsigned short* __restrict__ Wt) {
    int id = blockIdx.x * 256 + threadIdx.x;  // 4*512*512
    int l = id >> 18;
    int n = (id >> 9) & 511;
    int k = id & 511;
    Wt[id] = f2bf(W[((size_t)l << 18) + ((size_t)k << 9) + n]);
}

// ---------------- Neighbor aggregate + combine + bf16 convert ----------------
// t[n,:] = bf16( h[n,:] + (1/max(indeg,1)) * sum_{e: dst=n} (h[src[e],:] + he[e,:]) )
__global__ void k_neigh(const float* __restrict__ h, const int* __restrict__ eid,
                        const int* __restrict__ rs, const int* __restrict__ src,
                        const int* __restrict__ hedge, const float* __restrict__ bemb,
                        unsigned short* __restrict__ t) {
    int n = blockIdx.x;
    int c = threadIdx.x * 4;  // 128 threads
    int s = rs[n], e = rs[n + 1];
    float4 acc = make_float4(0.f, 0.f, 0.f, 0.f);
    for (int j = s; j < e; ++j) {
        int ed = eid[j];
        int sn = src[ed];
        int i0 = hedge[ed * 3 + 0];
        int i1 = hedge[ed * 3 + 1];
        int i2 = hedge[ed * 3 + 2];
        const float4 hv = *(const float4*)(h + (size_t)sn * HID + c);
        const float4 b0 = *(const float4*)(bemb + (size_t)(i0)*HID + c);
        const float4 b1 = *(const float4*)(bemb + (size_t)(8 + i1) * HID + c);
        const float4 b2 = *(const float4*)(bemb + (size_t)(16 + i2) * HID + c);
        acc.x += hv.x + b0.x + b1.x + b2.x;
        acc.y += hv.y + b0.y + b1.y + b2.y;
        acc.z += hv.z + b0.z + b1.z + b2.z;
        acc.w += hv.w + b0.w + b1.w + b2.w;
    }
    float inv = 1.0f / fmaxf((float)(e - s), 1.0f);
    const float4 hn = *(const float4*)(h + (size_t)n * HID + c);
    float4 tv;
    tv.x = hn.x + acc.x * inv;
    tv.y = hn.y + acc.y * inv;
    tv.z = hn.z + acc.z * inv;
    tv.w = hn.w + acc.w * inv;
    ushort4 pk;
    pk.x = f2bf(tv.x); pk.y = f2bf(tv.y); pk.z = f2bf(tv.z); pk.w = f2bf(tv.w);
    *(ushort4*)(t + (size_t)n * HID + c) = pk;
}

// ---------------- GEMM: r[M,512] = A_bf16[M,512] @ W[k,n] + bias ----------------
// A k-contiguous rows; B staged from pre-transposed Wt[n][k] (also k-contiguous).
#define BM 128
#define BN 128
#define BK 32
#define PK 40  // padded LDS row (bf16 elems): 80B stride, 16B-aligned, bank-balanced

__global__ __launch_bounds__(256) void k_gemm(const unsigned short* __restrict__ A,
                                              const unsigned short* __restrict__ Bt,
                                              const float* __restrict__ bias,
                                              float* __restrict__ C) {
    __shared__ unsigned short As[BM * PK];
    __shared__ unsigned short Bs[BN * PK];
    const int tid = threadIdx.x;
    const int m0 = blockIdx.x * BM;
    const int n0 = blockIdx.y * BN;
    const int w = tid >> 6, lane = tid & 63;
    const int wm = (w >> 1) * 64, wn = (w & 1) * 64;
    const int lr = lane & 15, lg = lane >> 4;

    const int row_a = tid >> 2;       // 0..63
    const int gre = (tid & 3) * 8;    // k-granule elem offset

    f32x4 acc[4][4] = {};

    for (int k0 = 0; k0 < HID; k0 += BK) {
        __syncthreads();
        const float4 va0 = *(const float4*)(A + (size_t)(m0 + row_a) * HID + k0 + gre);
        const float4 va1 = *(const float4*)(A + (size_t)(m0 + row_a + 64) * HID + k0 + gre);
        const float4 vb0 = *(const float4*)(Bt + (size_t)(n0 + row_a) * HID + k0 + gre);
        const float4 vb1 = *(const float4*)(Bt + (size_t)(n0 + row_a + 64) * HID + k0 + gre);
        *(float4*)(As + row_a * PK + gre) = va0;
        *(float4*)(As + (row_a + 64) * PK + gre) = va1;
        *(float4*)(Bs + row_a * PK + gre) = vb0;
        *(float4*)(Bs + (row_a + 64) * PK + gre) = vb1;
        __syncthreads();

        bf16x8 af[4], bfr[4];
        for (int i = 0; i < 4; ++i)
            af[i] = *(const bf16x8*)(As + (wm + i * 16 + lr) * PK + lg * 8);
        for (int j = 0; j < 4; ++j)
            bfr[j] = *(const bf16x8*)(Bs + (wn + j * 16 + lr) * PK + lg * 8);
        for (int i = 0; i < 4; ++i)
            for (int j = 0; j < 4; ++j)
                acc[i][j] = __builtin_amdgcn_mfma_f32_16x16x32_bf16(af[i], bfr[j], acc[i][j], 0, 0, 0);
    }

    for (int i = 0; i < 4; ++i) {
        const int grow = m0 + wm + i * 16 + lg * 4;
        for (int j = 0; j < 4; ++j) {
            const int gcol = n0 + wn + j * 16 + lr;
            const float bv = bias[gcol];
            for (int rr = 0; rr < 4; ++rr)
                C[(size_t)(grow + rr) * HID + gcol] = acc[i][j][rr] + bv;
        }
    }
}

// ---------------- GraphNorm + (ReLU) + residual (+ pool on last layer) ----------------
__global__ __launch_bounds__(512) void k_gnorm(const float* __restrict__ r, float* __restrict__ h,
                                               const int* __restrict__ gs,
                                               const float* __restrict__ gw, const float* __restrict__ gb,
                                               const float* __restrict__ gms,
                                               float* __restrict__ pooled, int relu, int do_pool) {
    int g = blockIdx.x;
    int c = threadIdx.x;  // 512 threads = channels
    int s = gs[g], e = gs[g + 1];
    float cnt = fmaxf((float)(e - s), 1.0f);
    float sum = 0.f, sq = 0.f;
    for (int n = s; n < e; ++n) {
        float v = r[(size_t)n * HID + c];
        sum += v; sq += v * v;
    }
    float mean = sum / cnt;
    float a = gms[c];
    float am = a * mean;
    float var = sq / cnt - 2.f * am * mean + am * am;
    float wgt = gw[c] * rsqrtf(var + 1e-6f);
    float bb = gb[c];
    float psum = 0.f;
    for (int n = s; n < e; ++n) {
        size_t idx = (size_t)n * HID + c;
        float v = (r[idx] - am) * wgt + bb;
        if (relu) v = fmaxf(v, 0.f);
        float hnew = v + h[idx];
        h[idx] = hnew;
        psum += hnew;
    }
    if (do_pool) pooled[(size_t)g * HID + c] = psum;
}

// ---------------- Final projection: out[G,128] = pooled @ Wp + bp ----------------
__global__ void k_proj(const float* __restrict__ pooled, const float* __restrict__ Wp,
                       const float* __restrict__ bp, float* __restrict__ out) {
    int g = blockIdx.x;
    int o = threadIdx.x;  // 128 threads
    float acc = bp[o];
    const float* pr = pooled + (size_t)g * HID;
    for (int k = 0; k < HID; ++k) acc += pr[k] * Wp[k * NOUT + o];
    out[g * NOUT + o] = acc;
}

extern "C" void kernel_launch(void* const* d_in, const int* in_sizes, int n_in,
                              void* d_out, int out_size, void* d_ws, size_t ws_size,
                              hipStream_t stream) {
    const int*   h_node = (const int*)d_in[0];
    const int*   h_edge = (const int*)d_in[1];
    const int*   src    = (const int*)d_in[2];
    const int*   dst    = (const int*)d_in[3];
    const int*   gid    = (const int*)d_in[4];
    const float* aemb   = (const float*)d_in[5];
    const float* bemb   = (const float*)d_in[6];
    const float* W      = (const float*)d_in[7];
    const float* bias   = (const float*)d_in[8];
    const float* gnw    = (const float*)d_in[9];
    const float* gnb    = (const float*)d_in[10];
    const float* gnms   = (const float*)d_in[11];
    const float* Wp     = (const float*)d_in[12];
    const float* bp     = (const float*)d_in[13];
    float* out = (float*)d_out;

    char* ws = (char*)d_ws;
    size_t off = 0;
    auto alloc = [&](size_t bytes) -> char* {
        char* p = ws + off;
        off += (bytes + 255) & ~(size_t)255;
        return p;
    };
    float* h            = (float*)alloc((size_t)N_NODES * HID * 4);
    float* r            = (float*)alloc((size_t)N_NODES * HID * 4);
    unsigned short* t   = (unsigned short*)alloc((size_t)N_NODES * HID * 2);
    unsigned short* Wt  = (unsigned short*)alloc((size_t)NL * HID * HID * 2);
    int* eid            = (int*)alloc((size_t)N_EDGES * 4);
    int* rs             = (int*)alloc((size_t)(N_NODES + 1) * 4);
    int* cnt            = (int*)alloc((size_t)N_NODES * 4);
    int* fc             = (int*)alloc((size_t)N_NODES * 4);
    int* gs             = (int*)alloc((size_t)(NG + 1) * 4);
    float* pooled       = (float*)alloc((size_t)NG * HID * 4);

    hipMemsetAsync(cnt, 0, (size_t)N_NODES * 4, stream);
    hipMemsetAsync(fc, 0, (size_t)N_NODES * 4, stream);
    k_count<<<N_EDGES / 256, 256, 0, stream>>>(dst, cnt);
    k_scan<<<1, 256, 0, stream>>>(cnt, rs);
    k_fill<<<N_EDGES / 256, 256, 0, stream>>>(dst, rs, fc, eid);
    k_gstart<<<1, NG, 0, stream>>>(gid, gs);
    k_atom<<<N_NODES, 128, 0, stream>>>(h_node, aemb, h);
    k_wt<<<(NL * HID * HID) / 256, 256, 0, stream>>>(W, Wt);

    for (int i = 0; i < NL; ++i) {
        k_neigh<<<N_NODES, 128, 0, stream>>>(h, eid, rs, src, h_edge,
                                             bemb + (size_t)i * 3 * 8 * HID, t);
        dim3 gg(N_NODES / BM, HID / BN);
        k_gemm<<<gg, 256, 0, stream>>>(t, Wt + (size_t)i * HID * HID, bias + i * HID, r);
        k_gnorm<<<NG, HID, 0, stream>>>(r, h, gs, gnw + i * HID, gnb + i * HID, gnms + i * HID,
                                        pooled, (i < NL - 1) ? 1 : 0, (i == NL - 1) ? 1 : 0);
    }
    k_proj<<<NG, NOUT, 0, stream>>>(pooled, Wp, bp, out);
}

// Round 2
// 553.675 us; speedup vs baseline: 1.3293x; 1.3293x over previous
//
#include <hip/hip_runtime.h>

#define N_NODES 16384
#define N_EDGES 262144
#define HID 512
#define NG 256
#define NL 4
#define NOUT 128

typedef __attribute__((ext_vector_type(8))) short bf16x8;
typedef __attribute__((ext_vector_type(4))) float f32x4;
typedef __attribute__((ext_vector_type(8))) unsigned short u16x8;

static __device__ __forceinline__ unsigned short f2bf(float f) {
    unsigned int u = __float_as_uint(f);
    unsigned int r = (u + 0x7fffu + ((u >> 16) & 1u)) >> 16;
    return (unsigned short)r;
}
static __device__ __forceinline__ float bf2f(unsigned short s) {
    return __uint_as_float(((unsigned int)s) << 16);
}

// ---------------- CSR build (dst-grouped edge lists) ----------------
__global__ void k_count(const int* __restrict__ dst, int* __restrict__ cnt) {
    int e = blockIdx.x * 256 + threadIdx.x;
    atomicAdd(&cnt[dst[e]], 1);
}

__global__ void k_scan(const int* __restrict__ cnt, int* __restrict__ rs) {
    __shared__ int spre[256];
    int t = threadIdx.x;
    int base = t * 64;
    int s = 0;
    for (int i = 0; i < 64; ++i) s += cnt[base + i];
    spre[t] = s;
    __syncthreads();
    if (t == 0) {
        int run = 0;
        for (int i = 0; i < 256; ++i) { int v = spre[i]; spre[i] = run; run += v; }
        rs[N_NODES] = run;
    }
    __syncthreads();
    int run = spre[t];
    for (int i = 0; i < 64; ++i) { rs[base + i] = run; run += cnt[base + i]; }
}

__global__ void k_fill(const int* __restrict__ dst, const int* __restrict__ rs,
                       int* __restrict__ fc, int* __restrict__ eid) {
    int e = blockIdx.x * 256 + threadIdx.x;
    int d = dst[e];
    int pos = atomicAdd(&fc[d], 1);
    eid[rs[d] + pos] = e;
}

// pack per-CSR-slot edge record: (src node, bond combo index)
__global__ void k_eprep(const int* __restrict__ eid, const int* __restrict__ src,
                        const int* __restrict__ hedge, int2* __restrict__ ep) {
    int j = blockIdx.x * 256 + threadIdx.x;
    int ed = eid[j];
    int s = src[ed];
    int c = hedge[ed * 3 + 0] * 64 + hedge[ed * 3 + 1] * 8 + hedge[ed * 3 + 2];
    ep[j] = make_int2(s, c);
}

__global__ void k_gstart(const int* __restrict__ gid, int* __restrict__ gs) {
    int g = threadIdx.x;  // 256 threads, gid is sorted
    int lo = 0, hi = N_NODES;
    while (lo < hi) { int mid = (lo + hi) >> 1; if (gid[mid] < g) lo = mid + 1; else hi = mid; }
    gs[g] = lo;
    if (g == 0) gs[NG] = N_NODES;
}

// ---------------- Bond combo table: ctab[l][combo][c] = sum of 3 embeddings ----------------
__global__ void k_combo(const float* __restrict__ bemb, unsigned short* __restrict__ ctab) {
    int id = blockIdx.x * 256 + threadIdx.x;  // NL*512*512
    int c = id & 511;
    int combo = (id >> 9) & 511;
    int l = id >> 18;
    int i0 = combo >> 6, i1 = (combo >> 3) & 7, i2 = combo & 7;
    const float* bl = bemb + (size_t)l * 3 * 8 * HID;
    float v = bl[(size_t)i0 * HID + c] + bl[(size_t)(8 + i1) * HID + c] + bl[(size_t)(16 + i2) * HID + c];
    ctab[id] = f2bf(v);
}

// ---------------- Atom encoder: h[n,:] = sum_f atom_emb[f, idx, :] ----------------
__global__ void k_atom(const int* __restrict__ hn, const float* __restrict__ emb,
                       float* __restrict__ h, unsigned short* __restrict__ h_bf) {
    int n = blockIdx.x;
    int c = threadIdx.x * 4;  // 128 threads * float4 = 512
    float4 acc = make_float4(0.f, 0.f, 0.f, 0.f);
    for (int f = 0; f < 9; ++f) {
        int v = hn[n * 9 + f];
        const float4 ev = *(const float4*)(emb + (size_t)(f * 128 + v) * HID + c);
        acc.x += ev.x; acc.y += ev.y; acc.z += ev.z; acc.w += ev.w;
    }
    *(float4*)(h + (size_t)n * HID + c) = acc;
    ushort4 pk;
    pk.x = f2bf(acc.x); pk.y = f2bf(acc.y); pk.z = f2bf(acc.z); pk.w = f2bf(acc.w);
    *(ushort4*)(h_bf + (size_t)n * HID + c) = pk;
}

// ---------------- W transpose + bf16 convert: Wt[l][n][k] = W[l][k][n] ----------------
__global__ void k_wt(const float* __restrict__ W, unsigned short* __restrict__ Wt) {
    int id = blockIdx.x * 256 + threadIdx.x;  // 4*512*512
    int l = id >> 18;
    int n = (id >> 9) & 511;
    int k = id & 511;
    Wt[id] = f2bf(W[((size_t)l << 18) + ((size_t)k << 9) + n]);
}

// ---------------- Neighbor aggregate + combine + bf16 convert ----------------
// t[n,:] = bf16( h[n,:] + (1/max(indeg,1)) * sum_{e: dst=n} (h_bf[src[e],:] + ctab[combo,:]) )
// 4 nodes per 256-block; 64 lanes per node, 8 channels (16B) per lane.
__global__ __launch_bounds__(256) void k_neigh(const float* __restrict__ h,
                                               const unsigned short* __restrict__ h_bf,
                                               const int2* __restrict__ ep,
                                               const int* __restrict__ rs,
                                               const unsigned short* __restrict__ ctab,
                                               unsigned short* __restrict__ t) {
    int n = blockIdx.x * 4 + (threadIdx.x >> 6);
    int c = (threadIdx.x & 63) * 8;
    int s = rs[n], e = rs[n + 1];
    float acc[8] = {0.f, 0.f, 0.f, 0.f, 0.f, 0.f, 0.f, 0.f};
    int j = s;
    for (; j + 2 <= e; j += 2) {
        int2 p0 = ep[j];
        int2 p1 = ep[j + 1];
        u16x8 a0 = *(const u16x8*)(h_bf + (size_t)p0.x * HID + c);
        u16x8 b0 = *(const u16x8*)(ctab + (size_t)p0.y * HID + c);
        u16x8 a1 = *(const u16x8*)(h_bf + (size_t)p1.x * HID + c);
        u16x8 b1 = *(const u16x8*)(ctab + (size_t)p1.y * HID + c);
        #pragma unroll
        for (int q = 0; q < 8; ++q)
            acc[q] += (bf2f(a0[q]) + bf2f(b0[q])) + (bf2f(a1[q]) + bf2f(b1[q]));
    }
    if (j < e) {
        int2 p0 = ep[j];
        u16x8 a0 = *(const u16x8*)(h_bf + (size_t)p0.x * HID + c);
        u16x8 b0 = *(const u16x8*)(ctab + (size_t)p0.y * HID + c);
        #pragma unroll
        for (int q = 0; q < 8; ++q)
            acc[q] += bf2f(a0[q]) + bf2f(b0[q]);
    }
    float inv = 1.0f / fmaxf((float)(e - s), 1.0f);
    const float4 h0 = *(const float4*)(h + (size_t)n * HID + c);
    const float4 h1 = *(const float4*)(h + (size_t)n * HID + c + 4);
    u16x8 pk;
    pk[0] = f2bf(h0.x + acc[0] * inv);
    pk[1] = f2bf(h0.y + acc[1] * inv);
    pk[2] = f2bf(h0.z + acc[2] * inv);
    pk[3] = f2bf(h0.w + acc[3] * inv);
    pk[4] = f2bf(h1.x + acc[4] * inv);
    pk[5] = f2bf(h1.y + acc[5] * inv);
    pk[6] = f2bf(h1.z + acc[6] * inv);
    pk[7] = f2bf(h1.w + acc[7] * inv);
    *(u16x8*)(t + (size_t)n * HID + c) = pk;
}

// ---------------- GEMM: r[M,512] = A_bf16[M,512] @ W[k,n] + bias ----------------
#define BM 128
#define BN 128
#define BK 32
#define PK 40  // padded LDS row (bf16 elems): 80B stride, 16B-aligned, bank-balanced

__global__ __launch_bounds__(256) void k_gemm(const unsigned short* __restrict__ A,
                                              const unsigned short* __restrict__ Bt,
                                              const float* __restrict__ bias,
                                              float* __restrict__ C) {
    __shared__ unsigned short As[BM * PK];
    __shared__ unsigned short Bs[BN * PK];
    const int tid = threadIdx.x;
    const int m0 = blockIdx.x * BM;
    const int n0 = blockIdx.y * BN;
    const int w = tid >> 6, lane = tid & 63;
    const int wm = (w >> 1) * 64, wn = (w & 1) * 64;
    const int lr = lane & 15, lg = lane >> 4;

    const int row_a = tid >> 2;       // 0..63
    const int gre = (tid & 3) * 8;    // k-granule elem offset

    f32x4 acc[4][4] = {};

    for (int k0 = 0; k0 < HID; k0 += BK) {
        __syncthreads();
        const float4 va0 = *(const float4*)(A + (size_t)(m0 + row_a) * HID + k0 + gre);
        const float4 va1 = *(const float4*)(A + (size_t)(m0 + row_a + 64) * HID + k0 + gre);
        const float4 vb0 = *(const float4*)(Bt + (size_t)(n0 + row_a) * HID + k0 + gre);
        const float4 vb1 = *(const float4*)(Bt + (size_t)(n0 + row_a + 64) * HID + k0 + gre);
        *(float4*)(As + row_a * PK + gre) = va0;
        *(float4*)(As + (row_a + 64) * PK + gre) = va1;
        *(float4*)(Bs + row_a * PK + gre) = vb0;
        *(float4*)(Bs + (row_a + 64) * PK + gre) = vb1;
        __syncthreads();

        bf16x8 af[4], bfr[4];
        for (int i = 0; i < 4; ++i)
            af[i] = *(const bf16x8*)(As + (wm + i * 16 + lr) * PK + lg * 8);
        for (int j = 0; j < 4; ++j)
            bfr[j] = *(const bf16x8*)(Bs + (wn + j * 16 + lr) * PK + lg * 8);
        for (int i = 0; i < 4; ++i)
            for (int j = 0; j < 4; ++j)
                acc[i][j] = __builtin_amdgcn_mfma_f32_16x16x32_bf16(af[i], bfr[j], acc[i][j], 0, 0, 0);
    }

    for (int i = 0; i < 4; ++i) {
        const int grow = m0 + wm + i * 16 + lg * 4;
        for (int j = 0; j < 4; ++j) {
            const int gcol = n0 + wn + j * 16 + lr;
            const float bv = bias[gcol];
            for (int rr = 0; rr < 4; ++rr)
                C[(size_t)(grow + rr) * HID + gcol] = acc[i][j][rr] + bv;
        }
    }
}

// ---------------- GraphNorm + (ReLU) + residual (+ pool on last layer) ----------------
__global__ __launch_bounds__(512) void k_gnorm(const float* __restrict__ r, float* __restrict__ h,
                                               unsigned short* __restrict__ h_bf,
                                               const int* __restrict__ gs,
                                               const float* __restrict__ gw, const float* __restrict__ gb,
                                               const float* __restrict__ gms,
                                               float* __restrict__ pooled, int relu, int do_pool) {
    int g = blockIdx.x;
    int c = threadIdx.x;  // 512 threads = channels
    int s = gs[g], e = gs[g + 1];
    float cnt = fmaxf((float)(e - s), 1.0f);
    float sum = 0.f, sq = 0.f;
    for (int n = s; n < e; ++n) {
        float v = r[(size_t)n * HID + c];
        sum += v; sq += v * v;
    }
    float mean = sum / cnt;
    float a = gms[c];
    float am = a * mean;
    float var = sq / cnt - 2.f * am * mean + am * am;
    float wgt = gw[c] * rsqrtf(var + 1e-6f);
    float bb = gb[c];
    float psum = 0.f;
    for (int n = s; n < e; ++n) {
        size_t idx = (size_t)n * HID + c;
        float v = (r[idx] - am) * wgt + bb;
        if (relu) v = fmaxf(v, 0.f);
        float hnew = v + h[idx];
        h[idx] = hnew;
        h_bf[idx] = f2bf(hnew);
        psum += hnew;
    }
    if (do_pool) pooled[(size_t)g * HID + c] = psum;
}

// ---------------- Final projection: out[G,128] = pooled @ Wp + bp ----------------
__global__ void k_proj(const float* __restrict__ pooled, const float* __restrict__ Wp,
                       const float* __restrict__ bp, float* __restrict__ out) {
    int g = blockIdx.x;
    int o = threadIdx.x;  // 128 threads
    float acc = bp[o];
    const float* pr = pooled + (size_t)g * HID;
    for (int k = 0; k < HID; ++k) acc += pr[k] * Wp[k * NOUT + o];
    out[g * NOUT + o] = acc;
}

extern "C" void kernel_launch(void* const* d_in, const int* in_sizes, int n_in,
                              void* d_out, int out_size, void* d_ws, size_t ws_size,
                              hipStream_t stream) {
    const int*   h_node = (const int*)d_in[0];
    const int*   h_edge = (const int*)d_in[1];
    const int*   src    = (const int*)d_in[2];
    const int*   dst    = (const int*)d_in[3];
    const int*   gid    = (const int*)d_in[4];
    const float* aemb   = (const float*)d_in[5];
    const float* bemb   = (const float*)d_in[6];
    const float* W      = (const float*)d_in[7];
    const float* bias   = (const float*)d_in[8];
    const float* gnw    = (const float*)d_in[9];
    const float* gnb    = (const float*)d_in[10];
    const float* gnms   = (const float*)d_in[11];
    const float* Wp     = (const float*)d_in[12];
    const float* bp     = (const float*)d_in[13];
    float* out = (float*)d_out;

    char* ws = (char*)d_ws;
    size_t off = 0;
    auto alloc = [&](size_t bytes) -> char* {
        char* p = ws + off;
        off += (bytes + 255) & ~(size_t)255;
        return p;
    };
    float* h            = (float*)alloc((size_t)N_NODES * HID * 4);
    float* r            = (float*)alloc((size_t)N_NODES * HID * 4);
    unsigned short* t   = (unsigned short*)alloc((size_t)N_NODES * HID * 2);
    unsigned short* h_bf= (unsigned short*)alloc((size_t)N_NODES * HID * 2);
    unsigned short* Wt  = (unsigned short*)alloc((size_t)NL * HID * HID * 2);
    unsigned short* ctab= (unsigned short*)alloc((size_t)NL * 512 * HID * 2);
    int2* ep            = (int2*)alloc((size_t)N_EDGES * 8);
    int* eid            = (int*)alloc((size_t)N_EDGES * 4);
    int* rs             = (int*)alloc((size_t)(N_NODES + 1) * 4);
    int* cnt            = (int*)alloc((size_t)N_NODES * 4);
    int* fc             = (int*)alloc((size_t)N_NODES * 4);
    int* gs             = (int*)alloc((size_t)(NG + 1) * 4);
    float* pooled       = (float*)alloc((size_t)NG * HID * 4);

    hipMemsetAsync(cnt, 0, (size_t)N_NODES * 4, stream);
    hipMemsetAsync(fc, 0, (size_t)N_NODES * 4, stream);
    k_count<<<N_EDGES / 256, 256, 0, stream>>>(dst, cnt);
    k_scan<<<1, 256, 0, stream>>>(cnt, rs);
    k_fill<<<N_EDGES / 256, 256, 0, stream>>>(dst, rs, fc, eid);
    k_eprep<<<N_EDGES / 256, 256, 0, stream>>>(eid, src, h_edge, ep);
    k_gstart<<<1, NG, 0, stream>>>(gid, gs);
    k_atom<<<N_NODES, 128, 0, stream>>>(h_node, aemb, h, h_bf);
    k_wt<<<(NL * HID * HID) / 256, 256, 0, stream>>>(W, Wt);
    k_combo<<<(NL * 512 * HID) / 256, 256, 0, stream>>>(bemb, ctab);

    for (int i = 0; i < NL; ++i) {
        k_neigh<<<N_NODES / 4, 256, 0, stream>>>(h, h_bf, ep, rs,
                                                 ctab + (size_t)i * 512 * HID, t);
        dim3 gg(N_NODES / BM, HID / BN);
        k_gemm<<<gg, 256, 0, stream>>>(t, Wt + (size_t)i * HID * HID, bias + i * HID, r);
        k_gnorm<<<NG, HID, 0, stream>>>(r, h, h_bf, gs, gnw + i * HID, gnb + i * HID, gnms + i * HID,
                                        pooled, (i < NL - 1) ? 1 : 0, (i == NL - 1) ? 1 : 0);
    }
    k_proj<<<NG, NOUT, 0, stream>>>(pooled, Wp, bp, out);
}

// Round 3
// 538.991 us; speedup vs baseline: 1.3655x; 1.0272x over previous
//
#include <hip/hip_runtime.h>

#define N_NODES 16384
#define N_EDGES 262144
#define HID 512
#define NG 256
#define NL 4
#define NOUT 128

typedef __attribute__((ext_vector_type(8))) short bf16x8;
typedef __attribute__((ext_vector_type(4))) float f32x4;
typedef __attribute__((ext_vector_type(8))) unsigned short u16x8;

static __device__ __forceinline__ unsigned short f2bf(float f) {
    unsigned int u = __float_as_uint(f);
    unsigned int r = (u + 0x7fffu + ((u >> 16) & 1u)) >> 16;
    return (unsigned short)r;
}
static __device__ __forceinline__ float bf2f(unsigned short s) {
    return __uint_as_float(((unsigned int)s) << 16);
}

// ---------------- CSR build (dst-grouped edge lists) ----------------
__global__ void k_count(const int* __restrict__ dst, int* __restrict__ cnt) {
    int e = blockIdx.x * 256 + threadIdx.x;
    atomicAdd(&cnt[dst[e]], 1);
}

__global__ void k_scan(const int* __restrict__ cnt, int* __restrict__ rs) {
    __shared__ int spre[256];
    int t = threadIdx.x;
    int base = t * 64;
    int s = 0;
    for (int i = 0; i < 64; ++i) s += cnt[base + i];
    spre[t] = s;
    __syncthreads();
    if (t == 0) {
        int run = 0;
        for (int i = 0; i < 256; ++i) { int v = spre[i]; spre[i] = run; run += v; }
        rs[N_NODES] = run;
    }
    __syncthreads();
    int run = spre[t];
    for (int i = 0; i < 64; ++i) { rs[base + i] = run; run += cnt[base + i]; }
}

__global__ void k_fill(const int* __restrict__ dst, const int* __restrict__ rs,
                       int* __restrict__ fc, int* __restrict__ eid) {
    int e = blockIdx.x * 256 + threadIdx.x;
    int d = dst[e];
    int pos = atomicAdd(&fc[d], 1);
    eid[rs[d] + pos] = e;
}

// pack per-CSR-slot edge record: (src node, bond combo index)
__global__ void k_eprep(const int* __restrict__ eid, const int* __restrict__ src,
                        const int* __restrict__ hedge, int2* __restrict__ ep) {
    int j = blockIdx.x * 256 + threadIdx.x;
    int ed = eid[j];
    int s = src[ed];
    int c = hedge[ed * 3 + 0] * 64 + hedge[ed * 3 + 1] * 8 + hedge[ed * 3 + 2];
    ep[j] = make_int2(s, c);
}

__global__ void k_gstart(const int* __restrict__ gid, int* __restrict__ gs,
                         float* __restrict__ rcnt) {
    int g = threadIdx.x;  // 256 threads, gid is sorted
    int lo = 0, hi = N_NODES;
    while (lo < hi) { int mid = (lo + hi) >> 1; if (gid[mid] < g) lo = mid + 1; else hi = mid; }
    gs[g] = lo;
    if (g == 0) gs[NG] = N_NODES;
    __syncthreads();
    int e = (g == NG - 1) ? N_NODES : gs[g + 1];
    rcnt[g] = 1.0f / fmaxf((float)(e - lo), 1.0f);
}

// ---------------- Bond combo table: ctab[l][combo][c] = sum of 3 embeddings ----------------
__global__ void k_combo(const float* __restrict__ bemb, unsigned short* __restrict__ ctab) {
    int id = blockIdx.x * 256 + threadIdx.x;  // NL*512*512
    int c = id & 511;
    int combo = (id >> 9) & 511;
    int l = id >> 18;
    int i0 = combo >> 6, i1 = (combo >> 3) & 7, i2 = combo & 7;
    const float* bl = bemb + (size_t)l * 3 * 8 * HID;
    float v = bl[(size_t)i0 * HID + c] + bl[(size_t)(8 + i1) * HID + c] + bl[(size_t)(16 + i2) * HID + c];
    ctab[id] = f2bf(v);
}

// ---------------- Atom encoder: h[n,:] = sum_f atom_emb[f, idx, :] ----------------
__global__ void k_atom(const int* __restrict__ hn, const float* __restrict__ emb,
                       float* __restrict__ h, unsigned short* __restrict__ h_bf) {
    int n = blockIdx.x;
    int c = threadIdx.x * 4;  // 128 threads * float4 = 512
    float4 acc = make_float4(0.f, 0.f, 0.f, 0.f);
    for (int f = 0; f < 9; ++f) {
        int v = hn[n * 9 + f];
        const float4 ev = *(const float4*)(emb + (size_t)(f * 128 + v) * HID + c);
        acc.x += ev.x; acc.y += ev.y; acc.z += ev.z; acc.w += ev.w;
    }
    *(float4*)(h + (size_t)n * HID + c) = acc;
    ushort4 pk;
    pk.x = f2bf(acc.x); pk.y = f2bf(acc.y); pk.z = f2bf(acc.z); pk.w = f2bf(acc.w);
    *(ushort4*)(h_bf + (size_t)n * HID + c) = pk;
}

// ---------------- W transpose + bf16 convert: Wt[l][n][k] = W[l][k][n] ----------------
__global__ void k_wt(const float* __restrict__ W, unsigned short* __restrict__ Wt) {
    int id = blockIdx.x * 256 + threadIdx.x;  // 4*512*512
    int l = id >> 18;
    int n = (id >> 9) & 511;
    int k = id & 511;
    Wt[id] = f2bf(W[((size_t)l << 18) + ((size_t)k << 9) + n]);
}

// ---------------- Neighbor aggregate + combine + bf16 convert ----------------
__global__ __launch_bounds__(256) void k_neigh(const float* __restrict__ h,
                                               const unsigned short* __restrict__ h_bf,
                                               const int2* __restrict__ ep,
                                               const int* __restrict__ rs,
                                               const unsigned short* __restrict__ ctab,
                                               unsigned short* __restrict__ t) {
    int n = blockIdx.x * 4 + (threadIdx.x >> 6);
    int c = (threadIdx.x & 63) * 8;
    int s = rs[n], e = rs[n + 1];
    float acc[8] = {0.f, 0.f, 0.f, 0.f, 0.f, 0.f, 0.f, 0.f};
    int j = s;
    for (; j + 2 <= e; j += 2) {
        int2 p0 = ep[j];
        int2 p1 = ep[j + 1];
        u16x8 a0 = *(const u16x8*)(h_bf + (size_t)p0.x * HID + c);
        u16x8 b0 = *(const u16x8*)(ctab + (size_t)p0.y * HID + c);
        u16x8 a1 = *(const u16x8*)(h_bf + (size_t)p1.x * HID + c);
        u16x8 b1 = *(const u16x8*)(ctab + (size_t)p1.y * HID + c);
        #pragma unroll
        for (int q = 0; q < 8; ++q)
            acc[q] += (bf2f(a0[q]) + bf2f(b0[q])) + (bf2f(a1[q]) + bf2f(b1[q]));
    }
    if (j < e) {
        int2 p0 = ep[j];
        u16x8 a0 = *(const u16x8*)(h_bf + (size_t)p0.x * HID + c);
        u16x8 b0 = *(const u16x8*)(ctab + (size_t)p0.y * HID + c);
        #pragma unroll
        for (int q = 0; q < 8; ++q)
            acc[q] += bf2f(a0[q]) + bf2f(b0[q]);
    }
    float inv = 1.0f / fmaxf((float)(e - s), 1.0f);
    const float4 h0 = *(const float4*)(h + (size_t)n * HID + c);
    const float4 h1 = *(const float4*)(h + (size_t)n * HID + c + 4);
    u16x8 pk;
    pk[0] = f2bf(h0.x + acc[0] * inv);
    pk[1] = f2bf(h0.y + acc[1] * inv);
    pk[2] = f2bf(h0.z + acc[2] * inv);
    pk[3] = f2bf(h0.w + acc[3] * inv);
    pk[4] = f2bf(h1.x + acc[4] * inv);
    pk[5] = f2bf(h1.y + acc[5] * inv);
    pk[6] = f2bf(h1.z + acc[6] * inv);
    pk[7] = f2bf(h1.w + acc[7] * inv);
    *(u16x8*)(t + (size_t)n * HID + c) = pk;
}

// ---------------- GEMM: r[M,512] = A_bf16[M,512] @ W[k,n] + bias ----------------
#define BM 128
#define BN 128
#define BK 32
#define PK 40

__global__ __launch_bounds__(256) void k_gemm(const unsigned short* __restrict__ A,
                                              const unsigned short* __restrict__ Bt,
                                              const float* __restrict__ bias,
                                              float* __restrict__ C) {
    __shared__ unsigned short As[BM * PK];
    __shared__ unsigned short Bs[BN * PK];
    const int tid = threadIdx.x;
    const int m0 = blockIdx.x * BM;
    const int n0 = blockIdx.y * BN;
    const int w = tid >> 6, lane = tid & 63;
    const int wm = (w >> 1) * 64, wn = (w & 1) * 64;
    const int lr = lane & 15, lg = lane >> 4;

    const int row_a = tid >> 2;
    const int gre = (tid & 3) * 8;

    f32x4 acc[4][4] = {};

    for (int k0 = 0; k0 < HID; k0 += BK) {
        __syncthreads();
        const float4 va0 = *(const float4*)(A + (size_t)(m0 + row_a) * HID + k0 + gre);
        const float4 va1 = *(const float4*)(A + (size_t)(m0 + row_a + 64) * HID + k0 + gre);
        const float4 vb0 = *(const float4*)(Bt + (size_t)(n0 + row_a) * HID + k0 + gre);
        const float4 vb1 = *(const float4*)(Bt + (size_t)(n0 + row_a + 64) * HID + k0 + gre);
        *(float4*)(As + row_a * PK + gre) = va0;
        *(float4*)(As + (row_a + 64) * PK + gre) = va1;
        *(float4*)(Bs + row_a * PK + gre) = vb0;
        *(float4*)(Bs + (row_a + 64) * PK + gre) = vb1;
        __syncthreads();

        bf16x8 af[4], bfr[4];
        for (int i = 0; i < 4; ++i)
            af[i] = *(const bf16x8*)(As + (wm + i * 16 + lr) * PK + lg * 8);
        for (int j = 0; j < 4; ++j)
            bfr[j] = *(const bf16x8*)(Bs + (wn + j * 16 + lr) * PK + lg * 8);
        for (int i = 0; i < 4; ++i)
            for (int j = 0; j < 4; ++j)
                acc[i][j] = __builtin_amdgcn_mfma_f32_16x16x32_bf16(af[i], bfr[j], acc[i][j], 0, 0, 0);
    }

    for (int i = 0; i < 4; ++i) {
        const int grow = m0 + wm + i * 16 + lg * 4;
        for (int j = 0; j < 4; ++j) {
            const int gcol = n0 + wn + j * 16 + lr;
            const float bv = bias[gcol];
            for (int rr = 0; rr < 4; ++rr)
                C[(size_t)(grow + rr) * HID + gcol] = acc[i][j][rr] + bv;
        }
    }
}

// ---------------- GraphNorm stats: gsum/gsq[g][c] via 8-way split + atomics ----------------
__global__ __launch_bounds__(256) void k_gstats(const float* __restrict__ r,
                                                const int* __restrict__ gs,
                                                float* __restrict__ gsum, float* __restrict__ gsq) {
    int g = blockIdx.x;
    int seg = blockIdx.y;
    int s = gs[g], e = gs[g + 1];
    int c = threadIdx.x * 2;
    float s0 = 0.f, s1 = 0.f, q0 = 0.f, q1 = 0.f;
    for (int n = s + seg; n < e; n += 8) {
        float2 v = *(const float2*)(r + (size_t)n * HID + c);
        s0 += v.x; s1 += v.y; q0 += v.x * v.x; q1 += v.y * v.y;
    }
    atomicAdd(&gsum[(size_t)g * HID + c], s0);
    atomicAdd(&gsum[(size_t)g * HID + c + 1], s1);
    atomicAdd(&gsq[(size_t)g * HID + c], q0);
    atomicAdd(&gsq[(size_t)g * HID + c + 1], q1);
}

// ---------------- GraphNorm apply + (ReLU) + residual ----------------
__global__ __launch_bounds__(256) void k_gapply(const float* __restrict__ r, float* __restrict__ h,
                                                unsigned short* __restrict__ h_bf,
                                                const int* __restrict__ gid,
                                                const float* __restrict__ rcnt,
                                                const float* __restrict__ gsum, const float* __restrict__ gsq,
                                                const float* __restrict__ gw, const float* __restrict__ gb,
                                                const float* __restrict__ gms, int relu) {
    int n = blockIdx.x * 2 + (threadIdx.x >> 7);
    int c = (threadIdx.x & 127) * 4;
    int g = gid[n];
    float rc = rcnt[g];
    const float4 sm = *(const float4*)(gsum + (size_t)g * HID + c);
    const float4 sq = *(const float4*)(gsq + (size_t)g * HID + c);
    const float4 ms = *(const float4*)(gms + c);
    const float4 gwv = *(const float4*)(gw + c);
    const float4 gbv = *(const float4*)(gb + c);
    const float4 rv = *(const float4*)(r + (size_t)n * HID + c);
    const float4 hv = *(const float4*)(h + (size_t)n * HID + c);
    float4 outv;
    float mean, am, var, wgt, v;
    #define CH(X, MSX, GWX, GBX, RX, HX, OX)                        \
        mean = sm.X * rc; am = ms.MSX * mean;                       \
        var = sq.X * rc - 2.f * am * mean + am * am;                \
        wgt = gwv.GWX * rsqrtf(var + 1e-6f);                        \
        v = (rv.RX - am) * wgt + gbv.GBX;                           \
        if (relu) v = fmaxf(v, 0.f);                                \
        outv.OX = v + hv.HX;
    CH(x, x, x, x, x, x, x)
    CH(y, y, y, y, y, y, y)
    CH(z, z, z, z, z, z, z)
    CH(w, w, w, w, w, w, w)
    #undef CH
    *(float4*)(h + (size_t)n * HID + c) = outv;
    ushort4 pk;
    pk.x = f2bf(outv.x); pk.y = f2bf(outv.y); pk.z = f2bf(outv.z); pk.w = f2bf(outv.w);
    *(ushort4*)(h_bf + (size_t)n * HID + c) = pk;
}

// ---------------- Sum pooling: pooled[g][c] = sum_n h[n][c] ----------------
__global__ __launch_bounds__(128) void k_pool(const float* __restrict__ h,
                                              const int* __restrict__ gs,
                                              float* __restrict__ pooled) {
    int g = blockIdx.x;
    int seg = blockIdx.y;
    int s = gs[g], e = gs[g + 1];
    int c = threadIdx.x * 4;
    float4 acc = make_float4(0.f, 0.f, 0.f, 0.f);
    for (int n = s + seg; n < e; n += 8) {
        const float4 v = *(const float4*)(h + (size_t)n * HID + c);
        acc.x += v.x; acc.y += v.y; acc.z += v.z; acc.w += v.w;
    }
    atomicAdd(&pooled[(size_t)g * HID + c], acc.x);
    atomicAdd(&pooled[(size_t)g * HID + c + 1], acc.y);
    atomicAdd(&pooled[(size_t)g * HID + c + 2], acc.z);
    atomicAdd(&pooled[(size_t)g * HID + c + 3], acc.w);
}

// ---------------- Final projection: out[G,128] = pooled @ Wp + bp ----------------
__global__ void k_proj(const float* __restrict__ pooled, const float* __restrict__ Wp,
                       const float* __restrict__ bp, float* __restrict__ out) {
    int g = blockIdx.x;
    int o = threadIdx.x;
    float acc = bp[o];
    const float* pr = pooled + (size_t)g * HID;
    #pragma unroll 8
    for (int k = 0; k < HID; ++k) acc += pr[k] * Wp[k * NOUT + o];
    out[g * NOUT + o] = acc;
}

extern "C" void kernel_launch(void* const* d_in, const int* in_sizes, int n_in,
                              void* d_out, int out_size, void* d_ws, size_t ws_size,
                              hipStream_t stream) {
    const int*   h_node = (const int*)d_in[0];
    const int*   h_edge = (const int*)d_in[1];
    const int*   src    = (const int*)d_in[2];
    const int*   dst    = (const int*)d_in[3];
    const int*   gid    = (const int*)d_in[4];
    const float* aemb   = (const float*)d_in[5];
    const float* bemb   = (const float*)d_in[6];
    const float* W      = (const float*)d_in[7];
    const float* bias   = (const float*)d_in[8];
    const float* gnw    = (const float*)d_in[9];
    const float* gnb    = (const float*)d_in[10];
    const float* gnms   = (const float*)d_in[11];
    const float* Wp     = (const float*)d_in[12];
    const float* bp     = (const float*)d_in[13];
    float* out = (float*)d_out;

    char* ws = (char*)d_ws;
    size_t off = 0;
    auto alloc = [&](size_t bytes) -> char* {
        char* p = ws + off;
        off += (bytes + 255) & ~(size_t)255;
        return p;
    };
    float* h            = (float*)alloc((size_t)N_NODES * HID * 4);
    float* r            = (float*)alloc((size_t)N_NODES * HID * 4);
    unsigned short* t   = (unsigned short*)alloc((size_t)N_NODES * HID * 2);
    unsigned short* h_bf= (unsigned short*)alloc((size_t)N_NODES * HID * 2);
    unsigned short* Wt  = (unsigned short*)alloc((size_t)NL * HID * HID * 2);
    unsigned short* ctab= (unsigned short*)alloc((size_t)NL * 512 * HID * 2);
    int2* ep            = (int2*)alloc((size_t)N_EDGES * 8);
    int* eid            = (int*)alloc((size_t)N_EDGES * 4);
    int* rs             = (int*)alloc((size_t)(N_NODES + 1) * 4);
    int* cnt            = (int*)alloc((size_t)N_NODES * 4);
    int* fc             = (int*)alloc((size_t)N_NODES * 4);
    int* gs             = (int*)alloc((size_t)(NG + 1) * 4);
    float* rcnt         = (float*)alloc((size_t)NG * 4);
    float* gstat        = (float*)alloc((size_t)NG * HID * 2 * 4);
    float* pooled       = (float*)alloc((size_t)NG * HID * 4);
    float* gsum = gstat;
    float* gsq  = gstat + (size_t)NG * HID;

    hipMemsetAsync(cnt, 0, (size_t)N_NODES * 4, stream);
    hipMemsetAsync(fc, 0, (size_t)N_NODES * 4, stream);
    hipMemsetAsync(pooled, 0, (size_t)NG * HID * 4, stream);
    k_count<<<N_EDGES / 256, 256, 0, stream>>>(dst, cnt);
    k_scan<<<1, 256, 0, stream>>>(cnt, rs);
    k_fill<<<N_EDGES / 256, 256, 0, stream>>>(dst, rs, fc, eid);
    k_eprep<<<N_EDGES / 256, 256, 0, stream>>>(eid, src, h_edge, ep);
    k_gstart<<<1, NG, 0, stream>>>(gid, gs, rcnt);
    k_atom<<<N_NODES, 128, 0, stream>>>(h_node, aemb, h, h_bf);
    k_wt<<<(NL * HID * HID) / 256, 256, 0, stream>>>(W, Wt);
    k_combo<<<(NL * 512 * HID) / 256, 256, 0, stream>>>(bemb, ctab);

    for (int i = 0; i < NL; ++i) {
        k_neigh<<<N_NODES / 4, 256, 0, stream>>>(h, h_bf, ep, rs,
                                                 ctab + (size_t)i * 512 * HID, t);
        dim3 gg(N_NODES / BM, HID / BN);
        k_gemm<<<gg, 256, 0, stream>>>(t, Wt + (size_t)i * HID * HID, bias + i * HID, r);
        hipMemsetAsync(gstat, 0, (size_t)NG * HID * 2 * 4, stream);
        k_gstats<<<dim3(NG, 8), 256, 0, stream>>>(r, gs, gsum, gsq);
        k_gapply<<<N_NODES / 2, 256, 0, stream>>>(r, h, h_bf, gid, rcnt, gsum, gsq,
                                                  gnw + i * HID, gnb + i * HID, gnms + i * HID,
                                                  (i < NL - 1) ? 1 : 0);
    }
    k_pool<<<dim3(NG, 8), 128, 0, stream>>>(h, gs, pooled);
    k_proj<<<NG, NOUT, 0, stream>>>(pooled, Wp, bp, out);
}

// Round 4
// 494.503 us; speedup vs baseline: 1.4884x; 1.0900x over previous
//
#include <hip/hip_runtime.h>

#define N_NODES 16384
#define N_EDGES 262144
#define HID 512
#define NG 256
#define NL 4
#define NOUT 128

typedef __attribute__((ext_vector_type(8))) short bf16x8;
typedef __attribute__((ext_vector_type(4))) float f32x4;
typedef __attribute__((ext_vector_type(8))) unsigned short u16x8;

static __device__ __forceinline__ unsigned short f2bf(float f) {
    unsigned int u = __float_as_uint(f);
    unsigned int r = (u + 0x7fffu + ((u >> 16) & 1u)) >> 16;
    return (unsigned short)r;
}
static __device__ __forceinline__ float bf2f(unsigned short s) {
    return __uint_as_float(((unsigned int)s) << 16);
}

// async 16B global -> LDS (wave-uniform LDS base + lane*16, per-lane global src)
static __device__ __forceinline__ void gload_lds16(const unsigned short* g, unsigned short* l) {
    __builtin_amdgcn_global_load_lds(
        (const __attribute__((address_space(1))) unsigned int*)(g),
        (__attribute__((address_space(3))) unsigned int*)(l), 16, 0, 0);
}

// ---------------- CSR build (dst-grouped edge lists) ----------------
__global__ void k_count(const int* __restrict__ dst, int* __restrict__ cnt) {
    int e = blockIdx.x * 256 + threadIdx.x;
    atomicAdd(&cnt[dst[e]], 1);
}

__global__ void k_scan(const int* __restrict__ cnt, int* __restrict__ rs) {
    __shared__ int spre[256];
    int t = threadIdx.x;
    int base = t * 64;
    int s = 0;
    for (int i = 0; i < 64; ++i) s += cnt[base + i];
    spre[t] = s;
    __syncthreads();
    if (t == 0) {
        int run = 0;
        for (int i = 0; i < 256; ++i) { int v = spre[i]; spre[i] = run; run += v; }
        rs[N_NODES] = run;
    }
    __syncthreads();
    int run = spre[t];
    for (int i = 0; i < 64; ++i) { rs[base + i] = run; run += cnt[base + i]; }
}

__global__ void k_fill(const int* __restrict__ dst, const int* __restrict__ rs,
                       int* __restrict__ fc, int* __restrict__ eid) {
    int e = blockIdx.x * 256 + threadIdx.x;
    int d = dst[e];
    int pos = atomicAdd(&fc[d], 1);
    eid[rs[d] + pos] = e;
}

__global__ void k_eprep(const int* __restrict__ eid, const int* __restrict__ src,
                        const int* __restrict__ hedge, int2* __restrict__ ep) {
    int j = blockIdx.x * 256 + threadIdx.x;
    int ed = eid[j];
    int s = src[ed];
    int c = hedge[ed * 3 + 0] * 64 + hedge[ed * 3 + 1] * 8 + hedge[ed * 3 + 2];
    ep[j] = make_int2(s, c);
}

__global__ void k_gstart(const int* __restrict__ gid, int* __restrict__ gs,
                         float* __restrict__ rcnt) {
    int g = threadIdx.x;  // 256 threads, gid is sorted
    int lo = 0, hi = N_NODES;
    while (lo < hi) { int mid = (lo + hi) >> 1; if (gid[mid] < g) lo = mid + 1; else hi = mid; }
    gs[g] = lo;
    if (g == 0) gs[NG] = N_NODES;
    __syncthreads();
    int e = (g == NG - 1) ? N_NODES : gs[g + 1];
    rcnt[g] = 1.0f / fmaxf((float)(e - lo), 1.0f);
}

// ---------------- Bond combo table ----------------
__global__ void k_combo(const float* __restrict__ bemb, unsigned short* __restrict__ ctab) {
    int id = blockIdx.x * 256 + threadIdx.x;  // NL*512*512
    int c = id & 511;
    int combo = (id >> 9) & 511;
    int l = id >> 18;
    int i0 = combo >> 6, i1 = (combo >> 3) & 7, i2 = combo & 7;
    const float* bl = bemb + (size_t)l * 3 * 8 * HID;
    float v = bl[(size_t)i0 * HID + c] + bl[(size_t)(8 + i1) * HID + c] + bl[(size_t)(16 + i2) * HID + c];
    ctab[id] = f2bf(v);
}

// ---------------- Atom encoder ----------------
__global__ void k_atom(const int* __restrict__ hn, const float* __restrict__ emb,
                       float* __restrict__ h, unsigned short* __restrict__ h_bf) {
    int n = blockIdx.x;
    int c = threadIdx.x * 4;
    float4 acc = make_float4(0.f, 0.f, 0.f, 0.f);
    for (int f = 0; f < 9; ++f) {
        int v = hn[n * 9 + f];
        const float4 ev = *(const float4*)(emb + (size_t)(f * 128 + v) * HID + c);
        acc.x += ev.x; acc.y += ev.y; acc.z += ev.z; acc.w += ev.w;
    }
    *(float4*)(h + (size_t)n * HID + c) = acc;
    ushort4 pk;
    pk.x = f2bf(acc.x); pk.y = f2bf(acc.y); pk.z = f2bf(acc.z); pk.w = f2bf(acc.w);
    *(ushort4*)(h_bf + (size_t)n * HID + c) = pk;
}

// ---------------- W transpose + bf16: Wt[l][n][k] = W[l][k][n] ----------------
__global__ void k_wt(const float* __restrict__ W, unsigned short* __restrict__ Wt) {
    int id = blockIdx.x * 256 + threadIdx.x;
    int l = id >> 18;
    int n = (id >> 9) & 511;
    int k = id & 511;
    Wt[id] = f2bf(W[((size_t)l << 18) + ((size_t)k << 9) + n]);
}

// ---------------- Neighbor aggregate + combine + bf16 ----------------
#define NEDGE1(PX, PY)                                                          \
    {                                                                           \
        u16x8 a0 = *(const u16x8*)(h_bf + (size_t)(PX)*HID + c);                \
        u16x8 b0 = *(const u16x8*)(ctab + (size_t)(PY)*HID + c);                \
        _Pragma("unroll") for (int q = 0; q < 8; ++q)                           \
            acc[q] += bf2f(a0[q]) + bf2f(b0[q]);                                \
    }

__global__ __launch_bounds__(256) void k_neigh(const float* __restrict__ h,
                                               const unsigned short* __restrict__ h_bf,
                                               const int2* __restrict__ ep,
                                               const int* __restrict__ rs,
                                               const unsigned short* __restrict__ ctab,
                                               unsigned short* __restrict__ t) {
    int n = blockIdx.x * 4 + (threadIdx.x >> 6);
    int c = (threadIdx.x & 63) * 8;
    int s = rs[n], e = rs[n + 1];
    const float4 h0 = *(const float4*)(h + (size_t)n * HID + c);
    const float4 h1 = *(const float4*)(h + (size_t)n * HID + c + 4);
    float acc[8] = {0.f, 0.f, 0.f, 0.f, 0.f, 0.f, 0.f, 0.f};
    int j = s;
    if (j < e && (j & 1)) {  // peel to 16B-align ep for int4 loads
        int2 p = ep[j];
        NEDGE1(p.x, p.y)
        ++j;
    }
    for (; j + 4 <= e; j += 4) {
        int4 pa = *(const int4*)(ep + j);      // edges j, j+1
        int4 pb = *(const int4*)(ep + j + 2);  // edges j+2, j+3
        u16x8 a0 = *(const u16x8*)(h_bf + (size_t)pa.x * HID + c);
        u16x8 b0 = *(const u16x8*)(ctab + (size_t)pa.y * HID + c);
        u16x8 a1 = *(const u16x8*)(h_bf + (size_t)pa.z * HID + c);
        u16x8 b1 = *(const u16x8*)(ctab + (size_t)pa.w * HID + c);
        u16x8 a2 = *(const u16x8*)(h_bf + (size_t)pb.x * HID + c);
        u16x8 b2 = *(const u16x8*)(ctab + (size_t)pb.y * HID + c);
        u16x8 a3 = *(const u16x8*)(h_bf + (size_t)pb.z * HID + c);
        u16x8 b3 = *(const u16x8*)(ctab + (size_t)pb.w * HID + c);
        #pragma unroll
        for (int q = 0; q < 8; ++q)
            acc[q] += ((bf2f(a0[q]) + bf2f(b0[q])) + (bf2f(a1[q]) + bf2f(b1[q])))
                    + ((bf2f(a2[q]) + bf2f(b2[q])) + (bf2f(a3[q]) + bf2f(b3[q])));
    }
    for (; j < e; ++j) {
        int2 p = ep[j];
        NEDGE1(p.x, p.y)
    }
    float inv = 1.0f / fmaxf((float)(e - s), 1.0f);
    u16x8 pk;
    pk[0] = f2bf(h0.x + acc[0] * inv);
    pk[1] = f2bf(h0.y + acc[1] * inv);
    pk[2] = f2bf(h0.z + acc[2] * inv);
    pk[3] = f2bf(h0.w + acc[3] * inv);
    pk[4] = f2bf(h1.x + acc[4] * inv);
    pk[5] = f2bf(h1.y + acc[5] * inv);
    pk[6] = f2bf(h1.z + acc[6] * inv);
    pk[7] = f2bf(h1.w + acc[7] * inv);
    *(u16x8*)(t + (size_t)n * HID + c) = pk;
}

// ---------------- GEMM: r_bf[M,512] = bf16(A @ W + bias) ----------------
// global_load_lds staging, BK=64, XOR-swizzled (granule ^= row&7, both sides).
#define BM 128
#define BN 64
#define BK 64

__global__ __launch_bounds__(256) void k_gemm(const unsigned short* __restrict__ A,
                                              const unsigned short* __restrict__ Bt,
                                              const float* __restrict__ bias,
                                              unsigned short* __restrict__ C) {
    __shared__ unsigned short As[BM * BK];  // 16 KB, linear, swizzled content
    __shared__ unsigned short Bs[BN * BK];  // 8 KB
    const int tid = threadIdx.x;
    const int m0 = blockIdx.x * BM;
    const int n0 = blockIdx.y * BN;
    const int w = tid >> 6, lane = tid & 63;
    const int wm = (w >> 1) * 64, wn = (w & 1) * 32;
    const int lr = lane & 15, lg = lane >> 4;

    // staging: round = 32 rows; thread t -> row tid>>3, granule tid&7 (linear LDS).
    // source column pre-swizzled so LDS[row][g] holds A[row][g ^ (row&7)].
    const int srow = tid >> 3;
    const int scol = ((tid & 7) ^ (srow & 7)) * 8;

    f32x4 acc[4][2] = {};

    for (int k0 = 0; k0 < HID; k0 += BK) {
        __syncthreads();  // all waves done reading previous tile
        #pragma unroll
        for (int r = 0; r < 4; ++r)
            gload_lds16(A + (size_t)(m0 + r * 32 + srow) * HID + k0 + scol,
                        As + r * 2048 + w * 512);
        #pragma unroll
        for (int r = 0; r < 2; ++r)
            gload_lds16(Bt + (size_t)(n0 + r * 32 + srow) * HID + k0 + scol,
                        Bs + r * 2048 + w * 512);
        __syncthreads();  // drains vmcnt(0): LDS tile ready

        #pragma unroll
        for (int kk = 0; kk < 2; ++kk) {
            bf16x8 af[4], bfr[2];
            #pragma unroll
            for (int i = 0; i < 4; ++i) {
                int row = wm + i * 16 + lr;
                af[i] = *(const bf16x8*)(As + row * BK + (((kk * 4 + lg) ^ (row & 7)) * 8));
            }
            #pragma unroll
            for (int j = 0; j < 2; ++j) {
                int row = wn + j * 16 + lr;
                bfr[j] = *(const bf16x8*)(Bs + row * BK + (((kk * 4 + lg) ^ (row & 7)) * 8));
            }
            #pragma unroll
            for (int i = 0; i < 4; ++i)
                #pragma unroll
                for (int j = 0; j < 2; ++j)
                    acc[i][j] = __builtin_amdgcn_mfma_f32_16x16x32_bf16(af[i], bfr[j], acc[i][j], 0, 0, 0);
        }
    }

    #pragma unroll
    for (int i = 0; i < 4; ++i) {
        const int grow = m0 + wm + i * 16 + lg * 4;
        #pragma unroll
        for (int j = 0; j < 2; ++j) {
            const int gcol = n0 + wn + j * 16 + lr;
            const float bv = bias[gcol];
            #pragma unroll
            for (int rr = 0; rr < 4; ++rr)
                C[(size_t)(grow + rr) * HID + gcol] = f2bf(acc[i][j][rr] + bv);
        }
    }
}

// ---------------- GraphNorm stats from bf16 r ----------------
__global__ __launch_bounds__(256) void k_gstats(const unsigned short* __restrict__ r,
                                                const int* __restrict__ gs,
                                                float* __restrict__ gsum, float* __restrict__ gsq) {
    int g = blockIdx.x;
    int seg = blockIdx.y;
    int s = gs[g], e = gs[g + 1];
    int c = threadIdx.x * 2;
    float s0 = 0.f, s1 = 0.f, q0 = 0.f, q1 = 0.f;
    for (int n = s + seg; n < e; n += 8) {
        ushort2 v = *(const ushort2*)(r + (size_t)n * HID + c);
        float v0 = bf2f(v.x), v1 = bf2f(v.y);
        s0 += v0; s1 += v1; q0 += v0 * v0; q1 += v1 * v1;
    }
    atomicAdd(&gsum[(size_t)g * HID + c], s0);
    atomicAdd(&gsum[(size_t)g * HID + c + 1], s1);
    atomicAdd(&gsq[(size_t)g * HID + c], q0);
    atomicAdd(&gsq[(size_t)g * HID + c + 1], q1);
}

// ---------------- GraphNorm apply + (ReLU) + residual ----------------
__global__ __launch_bounds__(256) void k_gapply(const unsigned short* __restrict__ r, float* __restrict__ h,
                                                unsigned short* __restrict__ h_bf,
                                                const int* __restrict__ gid,
                                                const float* __restrict__ rcnt,
                                                const float* __restrict__ gsum, const float* __restrict__ gsq,
                                                const float* __restrict__ gw, const float* __restrict__ gb,
                                                const float* __restrict__ gms, int relu) {
    int n = blockIdx.x * 2 + (threadIdx.x >> 7);
    int c = (threadIdx.x & 127) * 4;
    int g = gid[n];
    float rc = rcnt[g];
    const float4 sm = *(const float4*)(gsum + (size_t)g * HID + c);
    const float4 sq = *(const float4*)(gsq + (size_t)g * HID + c);
    const float4 ms = *(const float4*)(gms + c);
    const float4 gwv = *(const float4*)(gw + c);
    const float4 gbv = *(const float4*)(gb + c);
    const ushort4 rv4 = *(const ushort4*)(r + (size_t)n * HID + c);
    const float4 hv = *(const float4*)(h + (size_t)n * HID + c);
    float rv[4] = {bf2f(rv4.x), bf2f(rv4.y), bf2f(rv4.z), bf2f(rv4.w)};
    float4 outv;
    float mean, am, var, wgt, v;
    #define CH(X, K)                                                \
        mean = sm.X * rc; am = ms.X * mean;                         \
        var = sq.X * rc - 2.f * am * mean + am * am;                \
        wgt = gwv.X * rsqrtf(var + 1e-6f);                          \
        v = (rv[K] - am) * wgt + gbv.X;                             \
        if (relu) v = fmaxf(v, 0.f);                                \
        outv.X = v + hv.X;
    CH(x, 0)
    CH(y, 1)
    CH(z, 2)
    CH(w, 3)
    #undef CH
    *(float4*)(h + (size_t)n * HID + c) = outv;
    ushort4 pk;
    pk.x = f2bf(outv.x); pk.y = f2bf(outv.y); pk.z = f2bf(outv.z); pk.w = f2bf(outv.w);
    *(ushort4*)(h_bf + (size_t)n * HID + c) = pk;
}

// ---------------- Sum pooling ----------------
__global__ __launch_bounds__(128) void k_pool(const float* __restrict__ h,
                                              const int* __restrict__ gs,
                                              float* __restrict__ pooled) {
    int g = blockIdx.x;
    int seg = blockIdx.y;
    int s = gs[g], e = gs[g + 1];
    int c = threadIdx.x * 4;
    float4 acc = make_float4(0.f, 0.f, 0.f, 0.f);
    for (int n = s + seg; n < e; n += 8) {
        const float4 v = *(const float4*)(h + (size_t)n * HID + c);
        acc.x += v.x; acc.y += v.y; acc.z += v.z; acc.w += v.w;
    }
    atomicAdd(&pooled[(size_t)g * HID + c], acc.x);
    atomicAdd(&pooled[(size_t)g * HID + c + 1], acc.y);
    atomicAdd(&pooled[(size_t)g * HID + c + 2], acc.z);
    atomicAdd(&pooled[(size_t)g * HID + c + 3], acc.w);
}

// ---------------- Final projection ----------------
__global__ void k_proj(const float* __restrict__ pooled, const float* __restrict__ Wp,
                       const float* __restrict__ bp, float* __restrict__ out) {
    int g = blockIdx.x;
    int o = threadIdx.x;
    float acc = bp[o];
    const float* pr = pooled + (size_t)g * HID;
    #pragma unroll 8
    for (int k = 0; k < HID; ++k) acc += pr[k] * Wp[k * NOUT + o];
    out[g * NOUT + o] = acc;
}

extern "C" void kernel_launch(void* const* d_in, const int* in_sizes, int n_in,
                              void* d_out, int out_size, void* d_ws, size_t ws_size,
                              hipStream_t stream) {
    const int*   h_node = (const int*)d_in[0];
    const int*   h_edge = (const int*)d_in[1];
    const int*   src    = (const int*)d_in[2];
    const int*   dst    = (const int*)d_in[3];
    const int*   gid    = (const int*)d_in[4];
    const float* aemb   = (const float*)d_in[5];
    const float* bemb   = (const float*)d_in[6];
    const float* W      = (const float*)d_in[7];
    const float* bias   = (const float*)d_in[8];
    const float* gnw    = (const float*)d_in[9];
    const float* gnb    = (const float*)d_in[10];
    const float* gnms   = (const float*)d_in[11];
    const float* Wp     = (const float*)d_in[12];
    const float* bp     = (const float*)d_in[13];
    float* out = (float*)d_out;

    char* ws = (char*)d_ws;
    size_t off = 0;
    auto alloc = [&](size_t bytes) -> char* {
        char* p = ws + off;
        off += (bytes + 255) & ~(size_t)255;
        return p;
    };
    float* h            = (float*)alloc((size_t)N_NODES * HID * 4);
    unsigned short* rbf = (unsigned short*)alloc((size_t)N_NODES * HID * 2);
    unsigned short* t   = (unsigned short*)alloc((size_t)N_NODES * HID * 2);
    unsigned short* h_bf= (unsigned short*)alloc((size_t)N_NODES * HID * 2);
    unsigned short* Wt  = (unsigned short*)alloc((size_t)NL * HID * HID * 2);
    unsigned short* ctab= (unsigned short*)alloc((size_t)NL * 512 * HID * 2);
    int2* ep            = (int2*)alloc((size_t)N_EDGES * 8);
    int* eid            = (int*)alloc((size_t)N_EDGES * 4);
    int* rs             = (int*)alloc((size_t)(N_NODES + 1) * 4);
    int* cnt            = (int*)alloc((size_t)N_NODES * 4);
    int* fc             = (int*)alloc((size_t)N_NODES * 4);
    int* gs             = (int*)alloc((size_t)(NG + 1) * 4);
    float* rcnt         = (float*)alloc((size_t)NG * 4);
    float* gstat        = (float*)alloc((size_t)NG * HID * 2 * 4);
    float* pooled       = (float*)alloc((size_t)NG * HID * 4);
    float* gsum = gstat;
    float* gsq  = gstat + (size_t)NG * HID;

    hipMemsetAsync(cnt, 0, (size_t)N_NODES * 4, stream);
    hipMemsetAsync(fc, 0, (size_t)N_NODES * 4, stream);
    hipMemsetAsync(pooled, 0, (size_t)NG * HID * 4, stream);
    k_count<<<N_EDGES / 256, 256, 0, stream>>>(dst, cnt);
    k_scan<<<1, 256, 0, stream>>>(cnt, rs);
    k_fill<<<N_EDGES / 256, 256, 0, stream>>>(dst, rs, fc, eid);
    k_eprep<<<N_EDGES / 256, 256, 0, stream>>>(eid, src, h_edge, ep);
    k_gstart<<<1, NG, 0, stream>>>(gid, gs, rcnt);
    k_atom<<<N_NODES, 128, 0, stream>>>(h_node, aemb, h, h_bf);
    k_wt<<<(NL * HID * HID) / 256, 256, 0, stream>>>(W, Wt);
    k_combo<<<(NL * 512 * HID) / 256, 256, 0, stream>>>(bemb, ctab);

    for (int i = 0; i < NL; ++i) {
        k_neigh<<<N_NODES / 4, 256, 0, stream>>>(h, h_bf, ep, rs,
                                                 ctab + (size_t)i * 512 * HID, t);
        dim3 gg(N_NODES / BM, HID / BN);
        k_gemm<<<gg, 256, 0, stream>>>(t, Wt + (size_t)i * HID * HID, bias + i * HID, rbf);
        hipMemsetAsync(gstat, 0, (size_t)NG * HID * 2 * 4, stream);
        k_gstats<<<dim3(NG, 8), 256, 0, stream>>>(rbf, gs, gsum, gsq);
        k_gapply<<<N_NODES / 2, 256, 0, stream>>>(rbf, h, h_bf, gid, rcnt, gsum, gsq,
                                                  gnw + i * HID, gnb + i * HID, gnms + i * HID,
                                                  (i < NL - 1) ? 1 : 0);
    }
    k_pool<<<dim3(NG, 8), 128, 0, stream>>>(h, gs, pooled);
    k_proj<<<NG, NOUT, 0, stream>>>(pooled, Wp, bp, out);
}